// Round 2
// baseline (6718.795 us; speedup 1.0000x reference)
//
#include <hip/hip_runtime.h>
#include <math.h>

// ---------------------------------------------------------------------------
// Encoder_50414326120900: conv+BN(train)+ReLU x6, per-sample convT recon, losses
// Round 1: fp32 direct convs; ALL reductions via write-only partial slots +
// deterministic tree reduce (no atomics, no memset, no cross-replay state).
// Workspace peak ~403MB: y2[0,67.1M) y1[67.1M,100.7M) y3[67.1M,83.9M after y1
// dead) y5[0,50.3M after y2 dead); partials/doubles at float offset 100663296.
// ---------------------------------------------------------------------------

__device__ __forceinline__ float wave_reduce(float v) {
#pragma unroll
  for (int off = 32; off; off >>= 1) v += __shfl_down(v, off, 64);
  return v;
}

// ---------------- generic direct conv (raw output, no BN) -------------------
template <int CIN, int CIN_TOT, int COUT, int IH, int IW, int OH, int OW,
          int K, int STRIDE, int PAD, int CO_CHUNK, int CIN_STEP, int NT, int PPT>
__global__ __launch_bounds__(NT) void conv_raw_k(
    const float* __restrict__ in, int in_c0, const float* __restrict__ w,
    float* __restrict__ out) {
  static_assert(OH * OW == NT * PPT, "pixel mapping");
  static_assert(CIN % CIN_STEP == 0, "cin step");
  static_assert(COUT % CO_CHUNK == 0, "co chunk");
  constexpr int TIH = (OH - 1) * STRIDE + K;
  constexpr int TIW = (OW - 1) * STRIDE + K;
  __shared__ float tile[CIN_STEP][TIH][TIW + 1];
  const int b = blockIdx.x;
  const int co0 = blockIdx.y * CO_CHUNK;
  const int tid = threadIdx.x;

  float acc[PPT][CO_CHUNK];
#pragma unroll
  for (int p = 0; p < PPT; ++p)
#pragma unroll
    for (int co = 0; co < CO_CHUNK; ++co) acc[p][co] = 0.f;

  for (int c0 = 0; c0 < CIN; c0 += CIN_STEP) {
    __syncthreads();
    constexpr int TELEM = CIN_STEP * TIH * TIW;
    for (int i = tid; i < TELEM; i += NT) {
      int c = i / (TIH * TIW);
      int rr = i - c * (TIH * TIW);
      int r = rr / TIW, col = rr - r * TIW;
      int iy = r - PAD, ix = col - PAD;
      float v = 0.f;
      if (iy >= 0 && iy < IH && ix >= 0 && ix < IW)
        v = in[(((size_t)b * CIN_TOT + in_c0 + c0 + c) * IH + iy) * IW + ix];
      tile[c][r][col] = v;
    }
    __syncthreads();

    for (int c = 0; c < CIN_STEP; ++c) {
      float wreg[CO_CHUNK][K * K];
#pragma unroll
      for (int co = 0; co < CO_CHUNK; ++co)
#pragma unroll
        for (int j = 0; j < K * K; ++j)
          wreg[co][j] = w[((size_t)(co0 + co) * CIN + (c0 + c)) * (K * K) + j];
#pragma unroll
      for (int p = 0; p < PPT; ++p) {
        int pix = tid + p * NT;
        int oy = pix / OW, ox = pix - oy * OW;
#pragma unroll
        for (int ky = 0; ky < K; ++ky)
#pragma unroll
          for (int kx = 0; kx < K; ++kx) {
            float v = tile[c][oy * STRIDE + ky][ox * STRIDE + kx];
#pragma unroll
            for (int co = 0; co < CO_CHUNK; ++co)
              acc[p][co] = fmaf(v, wreg[co][ky * K + kx], acc[p][co]);
          }
      }
    }
  }
#pragma unroll
  for (int p = 0; p < PPT; ++p) {
    int pix = tid + p * NT;
#pragma unroll
    for (int co = 0; co < CO_CHUNK; ++co)
      out[((size_t)b * COUT + co0 + co) * (OH * OW) + pix] = acc[p][co];
  }
}

// ---------------- per-channel sum / sumsq -> partial slots (no atomics) -----
__global__ __launch_bounds__(256) void stats_k(const float* __restrict__ y,
                                               int C, int HW, int BHW, int NB,
                                               double* __restrict__ part) {
  __shared__ float sb1[4], sb2[4];
  const int c = blockIdx.x;
  float s = 0.f, q = 0.f;
  for (int i = blockIdx.y * 256 + threadIdx.x; i < BHW; i += NB * 256) {
    int b = i / HW, p = i - b * HW;
    float v = y[((size_t)b * C + c) * HW + p];
    s += v;
    q = fmaf(v, v, q);
  }
  s = wave_reduce(s);
  q = wave_reduce(q);
  int lane = threadIdx.x & 63, w = threadIdx.x >> 6;
  if (lane == 0) { sb1[w] = s; sb2[w] = q; }
  __syncthreads();
  if (threadIdx.x == 0) {
    size_t slot = ((size_t)c * NB + blockIdx.y) * 2;
    part[slot] = (double)(sb1[0] + sb1[1] + sb1[2] + sb1[3]);
    part[slot + 1] = (double)(sb2[0] + sb2[1] + sb2[2] + sb2[3]);
  }
}

// ---------------- BN scale/shift (serial deterministic slot sum) ------------
__global__ __launch_bounds__(256) void finalize_k(
    const double* __restrict__ part, int NB, const float* __restrict__ g,
    const float* __restrict__ bb, float* __restrict__ ss, int C, double invN) {
  int c = blockIdx.x * blockDim.x + threadIdx.x;
  if (c < C) {
    double s = 0.0, q = 0.0;
    for (int i = 0; i < NB; ++i) {
      s += part[((size_t)c * NB + i) * 2];
      q += part[((size_t)c * NB + i) * 2 + 1];
    }
    double mean = s * invN;
    double var = q * invN - mean * mean;
    float scale = g[c] * rsqrtf((float)var + 1e-5f);
    float shift = bb[c] - (float)mean * scale;
    ss[c] = scale;
    ss[C + c] = shift;
  }
}

// ---------------- normalize + relu (in place, float4) ----------------------
__global__ __launch_bounds__(256) void norm_relu_k(float* __restrict__ y,
                                                   const float* __restrict__ ss,
                                                   int C, int HW, long total) {
  long stride = (long)gridDim.x * 256 * 4;
  for (long i = ((long)blockIdx.x * 256 + threadIdx.x) * 4; i < total;
       i += stride) {
    int c = (int)((i / HW) % C);
    float sc = ss[c], sh = ss[C + c];
    float4 v = *(const float4*)(y + i);
    v.x = fmaxf(fmaf(v.x, sc, sh), 0.f);
    v.y = fmaxf(fmaf(v.y, sc, sh), 0.f);
    v.z = fmaxf(fmaf(v.z, sc, sh), 0.f);
    v.w = fmaxf(fmaf(v.w, sc, sh), 0.f);
    *(float4*)(y + i) = v;
  }
}

// ---------------- per-sample convT(stride2,pad3) + sigmoid-MSE -------------
__global__ __launch_bounds__(256) void convt_l1_k(const float* __restrict__ A,
                                                  const float* __restrict__ S,
                                                  const float* __restrict__ x,
                                                  double* __restrict__ l1p) {
  __shared__ float Ach[16][256];
  __shared__ float Sch[16][192];
  __shared__ float sb[4];
  const int b = blockIdx.x, tid = threadIdx.x;
  float acc[12];
#pragma unroll
  for (int k = 0; k < 12; ++k) acc[k] = 0.f;

  for (int d0 = 0; d0 < 64; d0 += 16) {
    __syncthreads();
#pragma unroll
    for (int k = 0; k < 16; ++k) {
      int i = tid + (k << 8);
      Ach[i >> 8][i & 255] = A[((size_t)b * 64 + d0 + (i >> 8)) * 256 + (i & 255)];
    }
#pragma unroll
    for (int k = 0; k < 12; ++k) {
      int i = tid + (k << 8);  // 3072 = 16 d * 192
      Sch[i / 192][i % 192] = S[((size_t)b * 192 + 3 * d0) * 64 + i];
    }
    __syncthreads();
#pragma unroll
    for (int k = 0; k < 12; ++k) {
      int q = tid + (k << 8);
      int t = q >> 10, r = q & 1023;
      int oy = r >> 5, ox = r & 31;
      int py = (oy + 3) & 1, px = (ox + 3) & 1;
      float a = acc[k];
#pragma unroll
      for (int di = 0; di < 16; ++di) {
        const float* Sd = &Sch[di][t << 6];
#pragma unroll
        for (int kyi = 0; kyi < 4; ++kyi) {
          int ky = py + 2 * kyi;
          int iy = (oy + 3 - ky) >> 1;
          if ((unsigned)iy < 16u) {
#pragma unroll
            for (int kxi = 0; kxi < 4; ++kxi) {
              int kx = px + 2 * kxi;
              int ix = (ox + 3 - kx) >> 1;
              if ((unsigned)ix < 16u)
                a = fmaf(Ach[di][(iy << 4) + ix], Sd[(ky << 3) + kx], a);
            }
          }
        }
      }
      acc[k] = a;
    }
  }
  float loc = 0.f;
#pragma unroll
  for (int k = 0; k < 12; ++k) {
    int q = tid + (k << 8);
    int t = q >> 10, r = q & 1023;
    float recon = 1.f / (1.f + expf(-acc[k]));
    float img = 1.f / (1.f + expf(-x[((size_t)b * 3 + t) * 1024 + r]));
    float d = img - recon;
    loc = fmaf(d, d, loc);
  }
  loc = wave_reduce(loc);
  if ((tid & 63) == 0) sb[tid >> 6] = loc;
  __syncthreads();
  if (tid == 0) l1p[b] = (double)(sb[0] + sb[1] + sb[2] + sb[3]);
}

// ---------------- l2 (mean relu) + l3 (entropy of softmax over d) ----------
__global__ __launch_bounds__(256) void loss23_k(const float* __restrict__ S,
                                                double* __restrict__ l2p,
                                                double* __restrict__ l3p) {
  __shared__ float sb1[4], sb2[4];
  int gid = blockIdx.x * 256 + threadIdx.x;  // exactly 196608 = 768*256
  int b = gid / 192;
  int r = gid - b * 192;
  int t = r >> 6, p = r & 63;
  const float* base = S + ((size_t)b * 192 + t) * 64 + p;
  float v[64];
  float l2 = 0.f, m = -1e30f;
#pragma unroll
  for (int d = 0; d < 64; ++d) {
    v[d] = base[(size_t)d * 192];
    m = fmaxf(m, v[d]);
    l2 += fmaxf(v[d], 0.f);
  }
  float Z = 0.f;
#pragma unroll
  for (int d = 0; d < 64; ++d) Z += expf(v[d] - m);
  float lZ = logf(Z);
  float l3 = 0.f;
#pragma unroll
  for (int d = 0; d < 64; ++d) {
    float lp = v[d] - m - lZ;
    l3 = fmaf(expf(lp), lp, l3);
  }
  l2 = wave_reduce(l2);
  l3 = wave_reduce(l3);
  int lane = threadIdx.x & 63, w = threadIdx.x >> 6;
  if (lane == 0) { sb1[w] = l2; sb2[w] = l3; }
  __syncthreads();
  if (threadIdx.x == 0) {
    l2p[blockIdx.x] = (double)(sb1[0] + sb1[1] + sb1[2] + sb1[3]);
    l3p[blockIdx.x] = (double)(sb2[0] + sb2[1] + sb2[2] + sb2[3]);
  }
}

// ---------------- deterministic final reduce of loss partials --------------
__global__ __launch_bounds__(256) void scalars_k(const double* __restrict__ l1p,
                                                 const double* __restrict__ l2p,
                                                 const double* __restrict__ l3p,
                                                 float* __restrict__ out) {
  __shared__ double sm[256];
  const int t = threadIdx.x;

  double a = 0.0;
  for (int i = t; i < 1024; i += 256) a += l1p[i];
  sm[t] = a;
  __syncthreads();
  for (int s = 128; s; s >>= 1) {
    if (t < s) sm[t] += sm[t + s];
    __syncthreads();
  }
  double L1 = sm[0];
  __syncthreads();

  a = 0.0;
  for (int i = t; i < 768; i += 256) a += l2p[i];
  sm[t] = a;
  __syncthreads();
  for (int s = 128; s; s >>= 1) {
    if (t < s) sm[t] += sm[t + s];
    __syncthreads();
  }
  double L2 = sm[0];
  __syncthreads();

  a = 0.0;
  for (int i = t; i < 768; i += 256) a += l3p[i];
  sm[t] = a;
  __syncthreads();
  for (int s = 128; s; s >>= 1) {
    if (t < s) sm[t] += sm[t + s];
    __syncthreads();
  }
  double L3 = sm[0];

  if (t == 0) {
    out[0] = (float)(0.1 * L1 / 3145728.0);   // l1: mean over B*3*32*32
    out[1] = (float)(0.1 * L2 / 12582912.0);  // l2: mean over S
    out[2] = (float)(-0.1 * L3 / 12582912.0); // l3: -mean(p*logp)
  }
}

// ---------------------------------------------------------------------------
extern "C" void kernel_launch(void* const* d_in, const int* in_sizes, int n_in,
                              void* d_out, int out_size, void* d_ws,
                              size_t ws_size, hipStream_t stream) {
  const float* x = (const float*)d_in[0];
  const float* w1 = (const float*)d_in[1];
  const float* w2 = (const float*)d_in[2];
  const float* w3 = (const float*)d_in[3];
  const float* wa = (const float*)d_in[4];
  const float* ws1 = (const float*)d_in[5];
  const float* ws2 = (const float*)d_in[6];
  const float* gb[12];
  for (int i = 0; i < 12; ++i) gb[i] = (const float*)d_in[7 + i];

  float* dout = (float*)d_out;
  float* Aout = dout;                  // [1024,64,16,16]
  float* Sout = dout + 16777216LL;     // [1024,192,8,8]
  float* sc_out = dout + 29360128LL;   // 3 scalars

  // workspace layout (floats)
  float* wsf = (float*)d_ws;
  float* y2 = wsf;                     // [0, 67,108,864)
  float* y1 = wsf + 67108864LL;        // [67.1M, 100.66M) — dead after L1
  float* y3 = wsf + 67108864LL;        // 16,777,216 f — reuses y1 region
  float* y5 = wsf;                     // 50,331,648 f — reuses y2 region
  double* part = (double*)(wsf + 100663296LL);  // 49,152 doubles (reused/layer)
  double* l1p = part + 49152;          // 1024
  double* l2p = l1p + 1024;            // 768
  double* l3p = l2p + 768;             // 768
  float* ssF = (float*)(l3p + 768);    // 384 floats (reused per layer)

  const int NB = 128;

  // ---- L0: conv1 3->32, 32x32, k3 s1 p1 ----
  conv_raw_k<3, 3, 32, 32, 32, 32, 32, 3, 1, 1, 8, 3, 256, 4>
      <<<dim3(1024, 4), 256, 0, stream>>>(x, 0, w1, y1);
  stats_k<<<dim3(32, NB), 256, 0, stream>>>(y1, 32, 1024, 1048576, NB, part);
  finalize_k<<<1, 256, 0, stream>>>(part, NB, gb[0], gb[1], ssF, 32, 1.0 / 1048576.0);
  norm_relu_k<<<8192, 256, 0, stream>>>(y1, ssF, 32, 1024, 33554432L);

  // ---- L1: conv2 32->64, 32x32 ----
  conv_raw_k<32, 32, 64, 32, 32, 32, 32, 3, 1, 1, 8, 8, 256, 4>
      <<<dim3(1024, 8), 256, 0, stream>>>(y1, 0, w2, y2);
  stats_k<<<dim3(64, NB), 256, 0, stream>>>(y2, 64, 1024, 1048576, NB, part);
  finalize_k<<<1, 256, 0, stream>>>(part, NB, gb[2], gb[3], ssF, 64, 1.0 / 1048576.0);
  norm_relu_k<<<8192, 256, 0, stream>>>(y2, ssF, 64, 1024, 67108864L);

  // ---- L2: conv3 64->64, 32x32 -> 16x16, s2 ----  (y1 dead; y3 takes its spot)
  conv_raw_k<64, 64, 64, 32, 32, 16, 16, 3, 2, 1, 8, 8, 256, 1>
      <<<dim3(1024, 8), 256, 0, stream>>>(y2, 0, w3, y3);
  stats_k<<<dim3(64, NB), 256, 0, stream>>>(y3, 64, 256, 262144, NB, part);
  finalize_k<<<1, 256, 0, stream>>>(part, NB, gb[4], gb[5], ssF, 64, 1.0 / 262144.0);
  norm_relu_k<<<4096, 256, 0, stream>>>(y3, ssF, 64, 256, 16777216L);

  // ---- L3: convA 32->64 (AS channels 0..31), 1x1 ----
  conv_raw_k<32, 64, 64, 16, 16, 16, 16, 1, 1, 0, 16, 16, 256, 1>
      <<<dim3(1024, 4), 256, 0, stream>>>(y3, 0, wa, Aout);
  stats_k<<<dim3(64, NB), 256, 0, stream>>>(Aout, 64, 256, 262144, NB, part);
  finalize_k<<<1, 256, 0, stream>>>(part, NB, gb[6], gb[7], ssF, 64, 1.0 / 262144.0);
  norm_relu_k<<<4096, 256, 0, stream>>>(Aout, ssF, 64, 256, 16777216L);

  // ---- L4: convS1 32->192 (AS channels 32..63), 16x16 ----  (y2 dead; y5)
  conv_raw_k<32, 64, 192, 16, 16, 16, 16, 3, 1, 1, 8, 8, 256, 1>
      <<<dim3(1024, 24), 256, 0, stream>>>(y3, 32, ws1, y5);
  stats_k<<<dim3(192, NB), 256, 0, stream>>>(y5, 192, 256, 262144, NB, part);
  finalize_k<<<1, 256, 0, stream>>>(part, NB, gb[8], gb[9], ssF, 192, 1.0 / 262144.0);
  norm_relu_k<<<8192, 256, 0, stream>>>(y5, ssF, 192, 256, 50331648L);

  // ---- L5: convS2 192->192, 16x16 -> 8x8, s2 ----
  conv_raw_k<192, 192, 192, 16, 16, 8, 8, 3, 2, 1, 8, 8, 64, 1>
      <<<dim3(1024, 24), 64, 0, stream>>>(y5, 0, ws2, Sout);
  stats_k<<<dim3(192, NB), 256, 0, stream>>>(Sout, 192, 64, 65536, NB, part);
  finalize_k<<<1, 256, 0, stream>>>(part, NB, gb[10], gb[11], ssF, 192, 1.0 / 65536.0);
  norm_relu_k<<<4096, 256, 0, stream>>>(Sout, ssF, 192, 64, 12582912L);

  // ---- losses (write-only partials, deterministic final reduce) ----
  convt_l1_k<<<1024, 256, 0, stream>>>(Aout, Sout, x, l1p);
  loss23_k<<<768, 256, 0, stream>>>(Sout, l2p, l3p);
  scalars_k<<<1, 256, 0, stream>>>(l1p, l2p, l3p, sc_out);
}

// Round 3
// 6148.773 us; speedup vs baseline: 1.0927x; 1.0927x over previous
//
#include <hip/hip_runtime.h>
#include <math.h>

// ---------------------------------------------------------------------------
// Encoder_50414326120900 — round 2: fp32 convs v2.
//  * padded LDS tile zeroed once, float4 staging, shift-only addressing
//  * BN(scale,shift)+ReLU fused into consumer conv staging (no norm pass on
//    intermediates); norm_relu kept only for A,S outputs
//  * weights via block-uniform indices -> scalar s_loads (SGPR fma operand)
//  * register blocking: 4px x 8co (stride-1), 1px x 8co x co-groups (stride-2)
//  ws layout (floats): y1[0,33.5M) y2[33.5M,100.66M) y3[0,16.8M)
//  y5[16.8M,67.1M) part@100,663,296 (46080 dbl) losses ss -> 403.045MB total
// ---------------------------------------------------------------------------

__device__ __forceinline__ float wave_reduce(float v) {
#pragma unroll
  for (int off = 32; off; off >>= 1) v += __shfl_down(v, off, 64);
  return v;
}

// ---------------- stride-1 3x3 conv, raw out, fused input-norm --------------
template <int CIN, int CIN_TOT, int IN_C0, int COUT, int OHW, int CIN_STEP,
          int IPB, bool NORM, int NT>
__global__ __launch_bounds__(NT) void conv3x3_s1_k(
    const float* __restrict__ in, const float* __restrict__ w,
    const float* __restrict__ ss, float* __restrict__ out) {
  constexpr int QW = OHW / 4;        // float4 quads per row
  constexpr int PIX_THR = OHW * QW;  // threads per image
  static_assert(NT == IPB * PIX_THR, "thread mapping");
  constexpr int TIH = OHW + 2;
  constexpr int TIW = (OHW + 2 + 3) & ~3;
  __shared__ __align__(16) float tile[IPB][CIN_STEP][TIH][TIW];

  const int tid = threadIdx.x;
  const int b0 = blockIdx.x * IPB;
  const int co0 = blockIdx.y * 8;
  const int im = tid / PIX_THR;
  const int it = tid % PIX_THR;
  const int row = it / QW;
  const int x0 = (it % QW) * 4;

  // zero entire tile once (borders stay zero across steps)
  constexpr int TF4 = IPB * CIN_STEP * TIH * TIW / 4;
  for (int i = tid; i < TF4; i += NT)
    *(float4*)((float*)tile + i * 4) = make_float4(0.f, 0.f, 0.f, 0.f);

  float acc[4][8];
#pragma unroll
  for (int p = 0; p < 4; ++p)
#pragma unroll
    for (int co = 0; co < 8; ++co) acc[p][co] = 0.f;

  for (int c0 = 0; c0 < CIN; c0 += CIN_STEP) {
    __syncthreads();
    constexpr int NLD = IPB * CIN_STEP * OHW * QW;
    for (int i = tid; i < NLD; i += NT) {
      int x4 = i % QW;
      int y = (i / QW) % OHW;
      int c = (i / (QW * OHW)) % CIN_STEP;
      int m = i / (QW * OHW * CIN_STEP);
      float4 v = *(const float4*)&in[(((size_t)(b0 + m) * CIN_TOT + IN_C0 +
                                       c0 + c) * OHW + y) * OHW + x4 * 4];
      if (NORM) {
        float sc = ss[IN_C0 + c0 + c], sh = ss[CIN_TOT + IN_C0 + c0 + c];
        v.x = fmaxf(fmaf(v.x, sc, sh), 0.f);
        v.y = fmaxf(fmaf(v.y, sc, sh), 0.f);
        v.z = fmaxf(fmaf(v.z, sc, sh), 0.f);
        v.w = fmaxf(fmaf(v.w, sc, sh), 0.f);
      }
      float* dst = &tile[m][c][y + 1][1 + x4 * 4];
      dst[0] = v.x; dst[1] = v.y; dst[2] = v.z; dst[3] = v.w;
    }
    __syncthreads();
#pragma unroll
    for (int c = 0; c < CIN_STEP; ++c) {
      const int cg = c0 + c;
#pragma unroll
      for (int ky = 0; ky < 3; ++ky) {
        const float* tr = &tile[im][c][row + ky][x0];
        float4 vlo = *(const float4*)tr;      // px x0..x0+3 (16B aligned)
        float2 vhi = *(const float2*)(tr + 4);
        float v[6] = {vlo.x, vlo.y, vlo.z, vlo.w, vhi.x, vhi.y};
#pragma unroll
        for (int kx = 0; kx < 3; ++kx) {
#pragma unroll
          for (int co = 0; co < 8; ++co) {
            float wv = w[((size_t)(co0 + co) * CIN + cg) * 9 + ky * 3 + kx];
#pragma unroll
            for (int p = 0; p < 4; ++p)
              acc[p][co] = fmaf(v[p + kx], wv, acc[p][co]);
          }
        }
      }
    }
  }
  const size_t ob =
      (((size_t)(b0 + im) * COUT + co0) * OHW + row) * OHW + x0;
#pragma unroll
  for (int co = 0; co < 8; ++co) {
    float4 o = make_float4(acc[0][co], acc[1][co], acc[2][co], acc[3][co]);
    *(float4*)&out[ob + (size_t)co * OHW * OHW] = o;
  }
}

// ---------------- stride-2 3x3 conv, raw out, fused input-norm --------------
template <int CIN, int COUT, int OWo, int CO_GROUPS, int CIN_STEP, bool NORM>
__global__ __launch_bounds__(256) void conv3x3_s2_k(
    const float* __restrict__ in, const float* __restrict__ w,
    const float* __restrict__ ss, float* __restrict__ out) {
  constexpr int IW = OWo * 2;
  constexpr int TIH = IW + 1;
  constexpr int TIW = (IW + 1 + 3) & ~3;
  constexpr int PIX = OWo * OWo;
  static_assert(CO_GROUPS * PIX == 256, "thread mapping");
  __shared__ __align__(16) float tile[CIN_STEP][TIH][TIW];

  const int tid = threadIdx.x;
  const int b = blockIdx.x;
  const int cog = tid / PIX;
  const int pix = tid % PIX;
  const int co0 = blockIdx.y * (CO_GROUPS * 8) + cog * 8;
  const int oy = pix / OWo;
  const int ox = pix % OWo;

  constexpr int TF4 = CIN_STEP * TIH * TIW / 4;
  for (int i = tid; i < TF4; i += 256)
    *(float4*)((float*)tile + i * 4) = make_float4(0.f, 0.f, 0.f, 0.f);

  float acc[8];
#pragma unroll
  for (int co = 0; co < 8; ++co) acc[co] = 0.f;

  for (int c0 = 0; c0 < CIN; c0 += CIN_STEP) {
    __syncthreads();
    constexpr int NLD = CIN_STEP * IW * (IW / 4);
    for (int i = tid; i < NLD; i += 256) {
      int x4 = i % (IW / 4);
      int y = (i / (IW / 4)) % IW;
      int c = i / (IW / 4 * IW);
      float4 v = *(const float4*)&in[(((size_t)b * CIN + c0 + c) * IW + y) *
                                     IW + x4 * 4];
      if (NORM) {
        float sc = ss[c0 + c], sh = ss[CIN + c0 + c];
        v.x = fmaxf(fmaf(v.x, sc, sh), 0.f);
        v.y = fmaxf(fmaf(v.y, sc, sh), 0.f);
        v.z = fmaxf(fmaf(v.z, sc, sh), 0.f);
        v.w = fmaxf(fmaf(v.w, sc, sh), 0.f);
      }
      float* dst = &tile[c][y + 1][1 + x4 * 4];
      dst[0] = v.x; dst[1] = v.y; dst[2] = v.z; dst[3] = v.w;
    }
    __syncthreads();
#pragma unroll
    for (int c = 0; c < CIN_STEP; ++c) {
      const int cg = c0 + c;
#pragma unroll
      for (int ky = 0; ky < 3; ++ky) {
        const float* tr = &tile[c][2 * oy + ky][2 * ox];
        float2 a = *(const float2*)tr;
        float2 bb = *(const float2*)(tr + 2);
        float v[3] = {a.x, a.y, bb.x};
#pragma unroll
        for (int kx = 0; kx < 3; ++kx) {
#pragma unroll
          for (int co = 0; co < 8; ++co) {
            float wv = w[((size_t)(co0 + co) * CIN + cg) * 9 + ky * 3 + kx];
            acc[co] = fmaf(v[kx], wv, acc[co]);
          }
        }
      }
    }
  }
#pragma unroll
  for (int co = 0; co < 8; ++co)
    out[((size_t)b * COUT + co0 + co) * PIX + pix] = acc[co];
}

// ---------------- 1x1 conv (L3), fused input-norm, no LDS ------------------
__global__ __launch_bounds__(256) void conv1x1_k(const float* __restrict__ in,
                                                 const float* __restrict__ w,
                                                 const float* __restrict__ ss,
                                                 float* __restrict__ out) {
  const int b = blockIdx.x;
  const int co0 = blockIdx.y * 16;
  const int pix = threadIdx.x;
  float acc[16];
#pragma unroll
  for (int co = 0; co < 16; ++co) acc[co] = 0.f;
#pragma unroll 8
  for (int c = 0; c < 32; ++c) {
    float v = in[((size_t)b * 64 + c) * 256 + pix];
    v = fmaxf(fmaf(v, ss[c], ss[64 + c]), 0.f);
#pragma unroll
    for (int co = 0; co < 16; ++co)
      acc[co] = fmaf(v, w[(co0 + co) * 32 + c], acc[co]);
  }
#pragma unroll
  for (int co = 0; co < 16; ++co)
    out[((size_t)b * 64 + co0 + co) * 256 + pix] = acc[co];
}

// ---------------- per-channel sum / sumsq -> partial slots ------------------
__global__ __launch_bounds__(256) void stats_k(const float* __restrict__ y,
                                               int C, int HW, int BHW, int NB,
                                               double* __restrict__ part) {
  __shared__ float sb1[4], sb2[4];
  const int c = blockIdx.x;
  float s = 0.f, q = 0.f;
  for (int i = blockIdx.y * 256 + threadIdx.x; i < BHW; i += NB * 256) {
    int b = i / HW, p = i - b * HW;
    float v = y[((size_t)b * C + c) * HW + p];
    s += v;
    q = fmaf(v, v, q);
  }
  s = wave_reduce(s);
  q = wave_reduce(q);
  int lane = threadIdx.x & 63, w = threadIdx.x >> 6;
  if (lane == 0) { sb1[w] = s; sb2[w] = q; }
  __syncthreads();
  if (threadIdx.x == 0) {
    size_t slot = ((size_t)c * NB + blockIdx.y) * 2;
    part[slot] = (double)(sb1[0] + sb1[1] + sb1[2] + sb1[3]);
    part[slot + 1] = (double)(sb2[0] + sb2[1] + sb2[2] + sb2[3]);
  }
}

// ---------------- BN scale/shift (serial deterministic slot sum) ------------
__global__ __launch_bounds__(256) void finalize_k(
    const double* __restrict__ part, int NB, const float* __restrict__ g,
    const float* __restrict__ bb, float* __restrict__ ss, int C, double invN) {
  int c = blockIdx.x * blockDim.x + threadIdx.x;
  if (c < C) {
    double s = 0.0, q = 0.0;
    for (int i = 0; i < NB; ++i) {
      s += part[((size_t)c * NB + i) * 2];
      q += part[((size_t)c * NB + i) * 2 + 1];
    }
    double mean = s * invN;
    double var = q * invN - mean * mean;
    float scale = g[c] * rsqrtf((float)var + 1e-5f);
    float shift = bb[c] - (float)mean * scale;
    ss[c] = scale;
    ss[C + c] = shift;
  }
}

// ---------------- normalize + relu (in place, float4) — A,S outputs only ---
__global__ __launch_bounds__(256) void norm_relu_k(float* __restrict__ y,
                                                   const float* __restrict__ ss,
                                                   int C, int HW, long total) {
  long stride = (long)gridDim.x * 256 * 4;
  for (long i = ((long)blockIdx.x * 256 + threadIdx.x) * 4; i < total;
       i += stride) {
    int c = (int)((i / HW) % C);
    float sc = ss[c], sh = ss[C + c];
    float4 v = *(const float4*)(y + i);
    v.x = fmaxf(fmaf(v.x, sc, sh), 0.f);
    v.y = fmaxf(fmaf(v.y, sc, sh), 0.f);
    v.z = fmaxf(fmaf(v.z, sc, sh), 0.f);
    v.w = fmaxf(fmaf(v.w, sc, sh), 0.f);
    *(float4*)(y + i) = v;
  }
}

// ---------------- per-sample convT(stride2,pad3) + sigmoid-MSE -------------
__global__ __launch_bounds__(256) void convt_l1_k(const float* __restrict__ A,
                                                  const float* __restrict__ S,
                                                  const float* __restrict__ x,
                                                  double* __restrict__ l1p) {
  __shared__ float Ach[16][256];
  __shared__ float Sch[16][192];
  __shared__ float sb[4];
  const int b = blockIdx.x, tid = threadIdx.x;
  float acc[12];
#pragma unroll
  for (int k = 0; k < 12; ++k) acc[k] = 0.f;

  for (int d0 = 0; d0 < 64; d0 += 16) {
    __syncthreads();
#pragma unroll
    for (int k = 0; k < 16; ++k) {
      int i = tid + (k << 8);
      Ach[i >> 8][i & 255] = A[((size_t)b * 64 + d0 + (i >> 8)) * 256 + (i & 255)];
    }
#pragma unroll
    for (int k = 0; k < 12; ++k) {
      int i = tid + (k << 8);  // 3072 = 16 d * 192
      Sch[i / 192][i % 192] = S[((size_t)b * 192 + 3 * d0) * 64 + i];
    }
    __syncthreads();
#pragma unroll
    for (int k = 0; k < 12; ++k) {
      int q = tid + (k << 8);
      int t = q >> 10, r = q & 1023;
      int oy = r >> 5, ox = r & 31;
      int py = (oy + 3) & 1, px = (ox + 3) & 1;
      float a = acc[k];
#pragma unroll
      for (int di = 0; di < 16; ++di) {
        const float* Sd = &Sch[di][t << 6];
#pragma unroll
        for (int kyi = 0; kyi < 4; ++kyi) {
          int ky = py + 2 * kyi;
          int iy = (oy + 3 - ky) >> 1;
          if ((unsigned)iy < 16u) {
#pragma unroll
            for (int kxi = 0; kxi < 4; ++kxi) {
              int kx = px + 2 * kxi;
              int ix = (ox + 3 - kx) >> 1;
              if ((unsigned)ix < 16u)
                a = fmaf(Ach[di][(iy << 4) + ix], Sd[(ky << 3) + kx], a);
            }
          }
        }
      }
      acc[k] = a;
    }
  }
  float loc = 0.f;
#pragma unroll
  for (int k = 0; k < 12; ++k) {
    int q = tid + (k << 8);
    int t = q >> 10, r = q & 1023;
    float recon = 1.f / (1.f + expf(-acc[k]));
    float img = 1.f / (1.f + expf(-x[((size_t)b * 3 + t) * 1024 + r]));
    float d = img - recon;
    loc = fmaf(d, d, loc);
  }
  loc = wave_reduce(loc);
  if ((tid & 63) == 0) sb[tid >> 6] = loc;
  __syncthreads();
  if (tid == 0) l1p[b] = (double)(sb[0] + sb[1] + sb[2] + sb[3]);
}

// ---------------- l2 (mean relu) + l3 (entropy of softmax over d) ----------
__global__ __launch_bounds__(256) void loss23_k(const float* __restrict__ S,
                                                double* __restrict__ l2p,
                                                double* __restrict__ l3p) {
  __shared__ float sb1[4], sb2[4];
  int gid = blockIdx.x * 256 + threadIdx.x;  // exactly 196608 = 768*256
  int b = gid / 192;
  int r = gid - b * 192;
  int t = r >> 6, p = r & 63;
  const float* base = S + ((size_t)b * 192 + t) * 64 + p;
  float v[64];
  float l2 = 0.f, m = -1e30f;
#pragma unroll
  for (int d = 0; d < 64; ++d) {
    v[d] = base[(size_t)d * 192];
    m = fmaxf(m, v[d]);
    l2 += fmaxf(v[d], 0.f);
  }
  float Z = 0.f;
#pragma unroll
  for (int d = 0; d < 64; ++d) Z += expf(v[d] - m);
  float lZ = logf(Z);
  float l3 = 0.f;
#pragma unroll
  for (int d = 0; d < 64; ++d) {
    float lp = v[d] - m - lZ;
    l3 = fmaf(expf(lp), lp, l3);
  }
  l2 = wave_reduce(l2);
  l3 = wave_reduce(l3);
  int lane = threadIdx.x & 63, w = threadIdx.x >> 6;
  if (lane == 0) { sb1[w] = l2; sb2[w] = l3; }
  __syncthreads();
  if (threadIdx.x == 0) {
    l2p[blockIdx.x] = (double)(sb1[0] + sb1[1] + sb1[2] + sb1[3]);
    l3p[blockIdx.x] = (double)(sb2[0] + sb2[1] + sb2[2] + sb2[3]);
  }
}

// ---------------- deterministic final reduce of loss partials --------------
__global__ __launch_bounds__(256) void scalars_k(const double* __restrict__ l1p,
                                                 const double* __restrict__ l2p,
                                                 const double* __restrict__ l3p,
                                                 float* __restrict__ out) {
  __shared__ double sm[256];
  const int t = threadIdx.x;

  double a = 0.0;
  for (int i = t; i < 1024; i += 256) a += l1p[i];
  sm[t] = a;
  __syncthreads();
  for (int s = 128; s; s >>= 1) {
    if (t < s) sm[t] += sm[t + s];
    __syncthreads();
  }
  double L1 = sm[0];
  __syncthreads();

  a = 0.0;
  for (int i = t; i < 768; i += 256) a += l2p[i];
  sm[t] = a;
  __syncthreads();
  for (int s = 128; s; s >>= 1) {
    if (t < s) sm[t] += sm[t + s];
    __syncthreads();
  }
  double L2 = sm[0];
  __syncthreads();

  a = 0.0;
  for (int i = t; i < 768; i += 256) a += l3p[i];
  sm[t] = a;
  __syncthreads();
  for (int s = 128; s; s >>= 1) {
    if (t < s) sm[t] += sm[t + s];
    __syncthreads();
  }
  double L3 = sm[0];

  if (t == 0) {
    out[0] = (float)(0.1 * L1 / 3145728.0);   // l1: mean over B*3*32*32
    out[1] = (float)(0.1 * L2 / 12582912.0);  // l2: mean over S
    out[2] = (float)(-0.1 * L3 / 12582912.0); // l3: -mean(p*logp)
  }
}

// ---------------------------------------------------------------------------
extern "C" void kernel_launch(void* const* d_in, const int* in_sizes, int n_in,
                              void* d_out, int out_size, void* d_ws,
                              size_t ws_size, hipStream_t stream) {
  const float* x = (const float*)d_in[0];
  const float* w1 = (const float*)d_in[1];
  const float* w2 = (const float*)d_in[2];
  const float* w3 = (const float*)d_in[3];
  const float* wa = (const float*)d_in[4];
  const float* ws1 = (const float*)d_in[5];
  const float* ws2 = (const float*)d_in[6];
  const float* gb[12];
  for (int i = 0; i < 12; ++i) gb[i] = (const float*)d_in[7 + i];

  float* dout = (float*)d_out;
  float* Aout = dout;                  // [1024,64,16,16]
  float* Sout = dout + 16777216LL;     // [1024,192,8,8]
  float* sc_out = dout + 29360128LL;   // 3 scalars

  // workspace layout (floats) — peak 403.045 MB (under round-1's 403.068)
  float* wsf = (float*)d_ws;
  float* y1 = wsf;                     // [0, 33,554,432)      L0 out, L1 in
  float* y2 = wsf + 33554432LL;        // [33.5M, 100.66M)     L1 out, L2 in
  float* y3 = wsf;                     // [0, 16,777,216)      L2 out (y1 dead)
  float* y5 = wsf + 16777216LL;        // [16.8M, 67.1M)       L4 out (y2 dead)
  double* part = (double*)(wsf + 100663296LL);  // 46,080 doubles (NB=120)
  double* l1p = part + 46080;          // 1024
  double* l2p = l1p + 1024;            // 768
  double* l3p = l2p + 768;             // 768
  float* ssA = (float*)(l3p + 768);    // 384 floats
  float* ssB = ssA + 384;              // 384 floats

  const int NB = 120;

  // ---- L0: conv1 3->32, 32x32 ----
  conv3x3_s1_k<3, 3, 0, 32, 32, 3, 1, false, 256>
      <<<dim3(1024, 4), 256, 0, stream>>>(x, w1, ssA, y1);
  stats_k<<<dim3(32, NB), 256, 0, stream>>>(y1, 32, 1024, 1048576, NB, part);
  finalize_k<<<1, 256, 0, stream>>>(part, NB, gb[0], gb[1], ssA, 32, 1.0 / 1048576.0);

  // ---- L1: conv2 32->64, 32x32 (stages y1 with ssA-norm) ----
  conv3x3_s1_k<32, 32, 0, 64, 32, 4, 1, true, 256>
      <<<dim3(1024, 8), 256, 0, stream>>>(y1, w2, ssA, y2);
  stats_k<<<dim3(64, NB), 256, 0, stream>>>(y2, 64, 1024, 1048576, NB, part);
  finalize_k<<<1, 256, 0, stream>>>(part, NB, gb[2], gb[3], ssB, 64, 1.0 / 1048576.0);

  // ---- L2: conv3 64->64, 32x32 -> 16x16 s2 (stages y2 with ssB) ----
  conv3x3_s2_k<64, 64, 16, 1, 4, true>
      <<<dim3(1024, 8), 256, 0, stream>>>(y2, w3, ssB, y3);
  stats_k<<<dim3(64, NB), 256, 0, stream>>>(y3, 64, 256, 262144, NB, part);
  finalize_k<<<1, 256, 0, stream>>>(part, NB, gb[4], gb[5], ssA, 64, 1.0 / 262144.0);
  // ssA = y3 stats; needed by L3 and L4

  // ---- L3: convA 32->64 (y3 ch 0..31), 1x1 ----
  conv1x1_k<<<dim3(1024, 4), 256, 0, stream>>>(y3, wa, ssA, Aout);
  stats_k<<<dim3(64, NB), 256, 0, stream>>>(Aout, 64, 256, 262144, NB, part);
  finalize_k<<<1, 256, 0, stream>>>(part, NB, gb[6], gb[7], ssB, 64, 1.0 / 262144.0);
  norm_relu_k<<<4096, 256, 0, stream>>>(Aout, ssB, 64, 256, 16777216L);

  // ---- L4: convS1 32->192 (y3 ch 32..63), 16x16 ----
  conv3x3_s1_k<32, 64, 32, 192, 16, 4, 2, true, 128>
      <<<dim3(512, 24), 128, 0, stream>>>(y3, ws1, ssA, y5);
  stats_k<<<dim3(192, NB), 256, 0, stream>>>(y5, 192, 256, 262144, NB, part);
  finalize_k<<<1, 256, 0, stream>>>(part, NB, gb[8], gb[9], ssB, 192, 1.0 / 262144.0);

  // ---- L5: convS2 192->192, 16x16 -> 8x8 s2 (stages y5 with ssB) ----
  conv3x3_s2_k<192, 192, 8, 4, 8, true>
      <<<dim3(1024, 6), 256, 0, stream>>>(y5, ws2, ssB, Sout);
  stats_k<<<dim3(192, NB), 256, 0, stream>>>(Sout, 192, 64, 65536, NB, part);
  finalize_k<<<1, 256, 0, stream>>>(part, NB, gb[10], gb[11], ssA, 192, 1.0 / 65536.0);
  norm_relu_k<<<4096, 256, 0, stream>>>(Sout, ssA, 192, 64, 12582912L);

  // ---- losses ----
  convt_l1_k<<<1024, 256, 0, stream>>>(Aout, Sout, x, l1p);
  loss23_k<<<768, 256, 0, stream>>>(Sout, l2p, l3p);
  scalars_k<<<1, 256, 0, stream>>>(l1p, l2p, l3p, sc_out);
}